// Round 11
// baseline (531.841 us; speedup 1.0000x reference)
//
#include <hip/hip_runtime.h>
#include <hip/hip_bf16.h>
#include <stdint.h>

#define N_NODES 8192
#define IN_F    256
#define OUT_F   64
#define NEG_SLOPE 0.2f
#define CAP     512       // per-wave neighbor list; mean degree 82, sd 9 -> 47 sigma

typedef unsigned int v4u __attribute__((ext_vector_type(4)));

// Non-temporal 16B load (R9: -15us on the adjacency stream).
static __device__ __forceinline__ v4u ntload(const v4u* p) {
    return __builtin_nontemporal_load(p);
}

static __device__ __forceinline__ float bf2f(unsigned short u) {
    union { unsigned int i; float f; } v; v.i = ((unsigned int)u) << 16; return v.f;
}
static __device__ __forceinline__ float bflo(unsigned int u) {
    union { unsigned int i; float f; } v; v.i = u << 16; return v.f;
}
static __device__ __forceinline__ float bfhi(unsigned int u) {
    union { unsigned int i; float f; } v; v.i = u & 0xFFFF0000u; return v.f;
}
static __device__ __forceinline__ unsigned short f2bf(float f) {
    union { float f; unsigned int i; } v; v.f = f;
    unsigned int x = v.i;
    unsigned int lsb = (x >> 16) & 1u;
    x += 0x7FFFu + lsb;
    return (unsigned short)(x >> 16);
}

// ---------------------------------------------------------------------------
// proj = X @ W (fp32 accum), s_i = proj @ a[:64], s_j = proj @ a[64:]
// 512 blocks x 16 rows (R5-verified compute). Detection fused in (batched
// uint4 prefix loads, one waitcnt): every block self-detects X dtype; block 0
// additionally detects adj width and plain-stores gflags for attn/probe
// (single writer, no atomics, no memset).
//   gflags[0]: adj violations — bit0 = not 4-byte elems (words in
//              {0,1,0x3F800000}), bit1 = not 2-byte, bit2 = not 1-byte.
//              width = 4 if !bit0 else 2 if !bit1 else 1.
//   gflags[1]: nonzero => X is fp32 (bf16-exp >= 133 occurs w.p. ~.48 per
//              fp32 mantissa half, never in bf16 N(0,1) data). R5-R10: fp32.
// ---------------------------------------------------------------------------
__global__ __launch_bounds__(256) void proj_kernel(
    const void* __restrict__ Xv, const void* __restrict__ Wv,
    const void* __restrict__ Av, const void* __restrict__ adjv,
    float* __restrict__ proj, float* __restrict__ si, float* __restrict__ sj,
    int* __restrict__ gflags) {
    __shared__ unsigned short wL[IN_F * OUT_F];  // 32 KB
    __shared__ unsigned short xL[16 * IN_F];     // 8 KB
    __shared__ float aL[2 * OUT_F];
    __shared__ int sdet[2];

    int tid = threadIdx.x;
    if (tid < 2) sdet[tid] = 0;
    __syncthreads();

    // ---- X dtype detect: 16KB prefix, 4 independent uint4/thread ----
    {
        const v4u* px = (const v4u*)Xv;
        v4u x0 = px[tid], x1 = px[tid + 256], x2 = px[tid + 512], x3 = px[tid + 768];
        int xf = 0;
#pragma unroll
        for (int k = 0; k < 4; ++k) {
            v4u a = (k == 0) ? x0 : (k == 1) ? x1 : (k == 2) ? x2 : x3;
#pragma unroll
            for (int h = 0; h < 4; ++h) {
                unsigned int v = (h == 0) ? a.x : (h == 1) ? a.y : (h == 2) ? a.z : a.w;
                unsigned int e0 = (v >> 7) & 0xFFu, e1 = (v >> 23) & 0xFFu;
                if (e0 >= 133u || e1 >= 133u) xf = 1;
            }
        }
        int viol = 0;
        if (blockIdx.x == 0) {   // adj width detect: block 0 only
            const v4u* pa = (const v4u*)adjv;
            v4u a0 = pa[tid], a1 = pa[tid + 256], a2 = pa[tid + 512], a3 = pa[tid + 768];
#pragma unroll
            for (int k = 0; k < 4; ++k) {
                v4u a = (k == 0) ? a0 : (k == 1) ? a1 : (k == 2) ? a2 : a3;
#pragma unroll
                for (int h = 0; h < 4; ++h) {
                    unsigned int v = (h == 0) ? a.x : (h == 1) ? a.y : (h == 2) ? a.z : a.w;
                    if (v) {
                        if (v != 1u && v != 0x3F800000u) viol |= 1;
                        unsigned int h0 = v & 0xFFFFu, h1 = v >> 16;
                        if ((h0 != 0u && h0 != 1u && h0 != 0x3F80u) ||
                            (h1 != 0u && h1 != 1u && h1 != 0x3F80u)) viol |= 2;
                        unsigned int b0 = v & 0xFFu, b1 = (v >> 8) & 0xFFu,
                                     b2 = (v >> 16) & 0xFFu, b3 = v >> 24;
                        if (b0 > 1u || b1 > 1u || b2 > 1u || b3 > 1u) viol |= 4;
                    }
                }
            }
        }
        for (int o = 32; o; o >>= 1) {
            xf   |= __shfl_xor(xf, o, 64);
            viol |= __shfl_xor(viol, o, 64);
        }
        if ((tid & 63) == 0) {
            if (xf)   atomicOr(&sdet[1], 1);
            if (viol) atomicOr(&sdet[0], viol);
        }
    }
    __syncthreads();
    bool xf32 = (sdet[1] != 0);
    if (blockIdx.x == 0 && tid == 0) { gflags[0] = sdet[0]; gflags[1] = sdet[1]; }

    int row0 = blockIdx.x * 16;
    int tc = tid & 15;
    int r  = tid >> 4;
    int c0 = tc * 4;
    int row = row0 + r;

    float acc0 = 0.f, acc1 = 0.f, acc2 = 0.f, acc3 = 0.f;

    if (xf32) {
        const float* Xf = (const float*)Xv;
        const float* Wf = (const float*)Wv;
        const float* Af = (const float*)Av;
        if (tid < 2 * OUT_F) aL[tid] = Af[tid];
        __syncthreads();
        const float4* xr = (const float4*)(Xf + (size_t)row * IN_F);
#pragma unroll 2
        for (int kv = 0; kv < IN_F / 4; ++kv) {
            float4 xq = xr[kv];
#pragma unroll
            for (int t = 0; t < 4; ++t) {
                float x = (t == 0) ? xq.x : (t == 1) ? xq.y : (t == 2) ? xq.z : xq.w;
                float4 wq = *(const float4*)(Wf + (size_t)(kv * 4 + t) * OUT_F + c0);
                acc0 = fmaf(x, wq.x, acc0);
                acc1 = fmaf(x, wq.y, acc1);
                acc2 = fmaf(x, wq.z, acc2);
                acc3 = fmaf(x, wq.w, acc3);
            }
        }
    } else {
        const unsigned short* Xh = (const unsigned short*)Xv;
        const unsigned short* Wh = (const unsigned short*)Wv;
        const unsigned short* Ah = (const unsigned short*)Av;
        for (int i = tid; i < (IN_F * OUT_F) / 8; i += 256)
            ((uint4*)wL)[i] = ((const uint4*)Wh)[i];
        for (int i = tid; i < (16 * IN_F) / 8; i += 256)
            ((uint4*)xL)[i] = ((const uint4*)(Xh + (size_t)row0 * IN_F))[i];
        if (tid < 2 * OUT_F) aL[tid] = bf2f(Ah[tid]);
        __syncthreads();

        const uint4* xrv = (const uint4*)&xL[r * IN_F];
#pragma unroll 4
        for (int kv = 0; kv < IN_F / 8; ++kv) {
            uint4 xq = xrv[kv];
#pragma unroll
            for (int h = 0; h < 4; ++h) {
                unsigned int xp = (h == 0) ? xq.x : (h == 1) ? xq.y : (h == 2) ? xq.z : xq.w;
                int k0 = kv * 8 + h * 2;
                uint2 w0 = *(const uint2*)&wL[(k0 + 0) * OUT_F + c0];
                uint2 w1 = *(const uint2*)&wL[(k0 + 1) * OUT_F + c0];
                float xa = bflo(xp), xb = bfhi(xp);
                acc0 = fmaf(xa, bflo(w0.x), acc0);
                acc1 = fmaf(xa, bfhi(w0.x), acc1);
                acc2 = fmaf(xa, bflo(w0.y), acc2);
                acc3 = fmaf(xa, bfhi(w0.y), acc3);
                acc0 = fmaf(xb, bflo(w1.x), acc0);
                acc1 = fmaf(xb, bfhi(w1.x), acc1);
                acc2 = fmaf(xb, bflo(w1.y), acc2);
                acc3 = fmaf(xb, bfhi(w1.y), acc3);
            }
        }
    }

    *(float4*)&proj[(size_t)row * OUT_F + c0] = make_float4(acc0, acc1, acc2, acc3);

    float sa = acc0 * aL[c0] + acc1 * aL[c0 + 1] + acc2 * aL[c0 + 2] + acc3 * aL[c0 + 3];
    float sb = acc0 * aL[OUT_F + c0] + acc1 * aL[OUT_F + c0 + 1] +
               acc2 * aL[OUT_F + c0 + 2] + acc3 * aL[OUT_F + c0 + 3];
    for (int off = 8; off; off >>= 1) {
        sa += __shfl_xor(sa, off, 16);
        sb += __shfl_xor(sb, off, 16);
    }
    if (tc == 0) { si[row] = sa; sj[row] = sb; }
}

// Index-only ballot compaction: no global loads, no score math in the scan.
static __device__ __forceinline__ void compact_idx(
    bool hit, int j, int lane, unsigned long long mask_lt,
    int& base, int* __restrict__ idxL) {
    unsigned long long b = __ballot(hit);
    if (hit) {
        int pos = base + (int)__popcll(b & mask_lt);
        if (pos < CAP) idxL[pos] = j;
    }
    base += (int)__popcll(b);
}

// ---------------------------------------------------------------------------
// Fused masked softmax + h_out = attn @ proj. ONE ROW PER WAVE, nt loads,
// no per-block detection (reads gflags). 2048 blocks x 4 waves. (R10 exact)
// ---------------------------------------------------------------------------
__global__ __launch_bounds__(256, 8) void attn_kernel(
    const void* __restrict__ adj, const int* __restrict__ gflags,
    const float* __restrict__ proj, const float* __restrict__ si_arr,
    const float* __restrict__ sj_arr, void* __restrict__ outv) {
    __shared__ int   s_idx[4 * CAP];   // 8 KB (2 KB per wave)
    __shared__ float s_sc[4 * CAP];    // 8 KB (2 KB per wave)

    int tid  = threadIdx.x;
    int lane = tid & 63;
    int wid  = tid >> 6;

    int f = gflags[0];
    int width = (!(f & 1)) ? 4 : ((!(f & 2)) ? 2 : 1);
    bool f32o = (gflags[1] != 0);

    int row = blockIdx.x * 4 + wid;
    int*   idxL = &s_idx[wid * CAP];
    float* scL  = &s_sc[wid * CAP];

    unsigned long long mask_lt = (1ull << lane) - 1ull;
    float si = si_arr[row];
    int base = 0;   // wave-uniform neighbor count

    if (width == 4) {
        const v4u* p = (const v4u*)((const unsigned int*)adj + (size_t)row * N_NODES);
        v4u c0 = ntload(p + lane), c1 = ntload(p + lane + 64),
            c2 = ntload(p + lane + 128), c3 = ntload(p + lane + 192);
#pragma unroll 1
        for (int it = 0; it < 8; ++it) {
            v4u n0, n1, n2, n3;
            if (it < 7) {
                int v = (it + 1) * 256 + lane;
                n0 = ntload(p + v); n1 = ntload(p + v + 64);
                n2 = ntload(p + v + 128); n3 = ntload(p + v + 192);
            }
#pragma unroll
            for (int q = 0; q < 4; ++q) {
                v4u c = (q == 0) ? c0 : (q == 1) ? c1 : (q == 2) ? c2 : c3;
                int j0 = 4 * (it * 256 + lane + q * 64);
                compact_idx(c.x != 0u, j0 + 0, lane, mask_lt, base, idxL);
                compact_idx(c.y != 0u, j0 + 1, lane, mask_lt, base, idxL);
                compact_idx(c.z != 0u, j0 + 2, lane, mask_lt, base, idxL);
                compact_idx(c.w != 0u, j0 + 3, lane, mask_lt, base, idxL);
            }
            c0 = n0; c1 = n1; c2 = n2; c3 = n3;
        }
    } else if (width == 2) {
        const v4u* p = (const v4u*)((const unsigned short*)adj + (size_t)row * N_NODES);
#pragma unroll 1
        for (int it = 0; it < 4; ++it) {
            int v0 = it * 256 + lane;
            v4u c0 = ntload(p + v0), c1 = ntload(p + v0 + 64),
                c2 = ntload(p + v0 + 128), c3 = ntload(p + v0 + 192);
#pragma unroll
            for (int q = 0; q < 4; ++q) {
                v4u c = (q == 0) ? c0 : (q == 1) ? c1 : (q == 2) ? c2 : c3;
                int j0 = 8 * (v0 + q * 64);
#pragma unroll
                for (int h = 0; h < 4; ++h) {
                    unsigned int word = (h == 0) ? c.x : (h == 1) ? c.y : (h == 2) ? c.z : c.w;
                    compact_idx((word & 0xFFFFu) != 0u, j0 + 2 * h + 0, lane, mask_lt, base, idxL);
                    compact_idx((word >> 16)     != 0u, j0 + 2 * h + 1, lane, mask_lt, base, idxL);
                }
            }
        }
    } else {
        const v4u* p = (const v4u*)((const unsigned char*)adj + (size_t)row * N_NODES);
#pragma unroll 1
        for (int it = 0; it < 2; ++it) {
            int v0 = it * 256 + lane;
            v4u c0 = ntload(p + v0), c1 = ntload(p + v0 + 64),
                c2 = ntload(p + v0 + 128), c3 = ntload(p + v0 + 192);
#pragma unroll
            for (int q = 0; q < 4; ++q) {
                v4u c = (q == 0) ? c0 : (q == 1) ? c1 : (q == 2) ? c2 : c3;
                int j0 = 16 * (v0 + q * 64);
#pragma unroll
                for (int h = 0; h < 4; ++h) {
                    unsigned int word = (h == 0) ? c.x : (h == 1) ? c.y : (h == 2) ? c.z : c.w;
                    compact_idx(((word)       & 0xFFu) != 0u, j0 + 4 * h + 0, lane, mask_lt, base, idxL);
                    compact_idx(((word >> 8)  & 0xFFu) != 0u, j0 + 4 * h + 1, lane, mask_lt, base, idxL);
                    compact_idx(((word >> 16) & 0xFFu) != 0u, j0 + 4 * h + 2, lane, mask_lt, base, idxL);
                    compact_idx(((word >> 24)        ) != 0u, j0 + 4 * h + 3, lane, mask_lt, base, idxL);
                }
            }
        }
    }

    int cnt = base;

    if (cnt == 0) {
        float acc = 0.f;
#pragma unroll 4
        for (int j = 0; j < N_NODES; ++j) acc += proj[(size_t)j * OUT_F + lane];
        float h = acc * (1.0f / (float)N_NODES);
        if (f32o) ((float*)outv)[(size_t)row * OUT_F + lane] = h;
        else ((unsigned short*)outv)[(size_t)row * OUT_F + lane] = f2bf(h);
        return;
    }

    if (cnt <= CAP) {
        float m = -3.0e38f;
        for (int k = lane; k < cnt; k += 64) {
            int j = idxL[k];
            float sc = si + sj_arr[j];
            sc = (sc >= 0.f) ? sc : NEG_SLOPE * sc;
            scL[k] = sc;
            m = fmaxf(m, sc);
        }
        for (int o = 32; o; o >>= 1) m = fmaxf(m, __shfl_xor(m, o, 64));

        float psum = 0.f;
        for (int k = lane; k < cnt; k += 64) {
            float w = expf(scL[k] - m);
            scL[k] = w;
            psum += w;
        }
        for (int o = 32; o; o >>= 1) psum += __shfl_xor(psum, o, 64);
        float inv_denom = 1.0f / psum;

        float acc = 0.f;
#pragma unroll 4
        for (int k = 0; k < cnt; ++k)
            acc = fmaf(scL[k], proj[(size_t)idxL[k] * OUT_F + lane], acc);
        float h = acc * inv_denom;
        if (f32o) ((float*)outv)[(size_t)row * OUT_F + lane] = h;
        else ((unsigned short*)outv)[(size_t)row * OUT_F + lane] = f2bf(h);
        return;
    }

    // ---- overflow fallback (cnt > CAP): correct, slow, statistically never hit.
    float m = -3.0e38f;
#pragma unroll 1
    for (int j = lane; j < N_NODES; j += 64) {
        unsigned int mu;
        if (width == 4)      mu = ((const unsigned int*)adj)[(size_t)row * N_NODES + j];
        else if (width == 2) mu = ((const unsigned short*)adj)[(size_t)row * N_NODES + j];
        else                 mu = ((const unsigned char*)adj)[(size_t)row * N_NODES + j];
        if (mu) {
            float sc = si + sj_arr[j];
            sc = (sc >= 0.f) ? sc : NEG_SLOPE * sc;
            m = fmaxf(m, sc);
        }
    }
    for (int o = 32; o; o >>= 1) m = fmaxf(m, __shfl_xor(m, o, 64));
    float psum = 0.f;
#pragma unroll 1
    for (int j = lane; j < N_NODES; j += 64) {
        unsigned int mu;
        if (width == 4)      mu = ((const unsigned int*)adj)[(size_t)row * N_NODES + j];
        else if (width == 2) mu = ((const unsigned short*)adj)[(size_t)row * N_NODES + j];
        else                 mu = ((const unsigned char*)adj)[(size_t)row * N_NODES + j];
        if (mu) {
            float sc = si + sj_arr[j];
            sc = (sc >= 0.f) ? sc : NEG_SLOPE * sc;
            psum += expf(sc - m);
        }
    }
    for (int o = 32; o; o >>= 1) psum += __shfl_xor(psum, o, 64);
    float acc = 0.f;
#pragma unroll 1
    for (int j = 0; j < N_NODES; ++j) {
        unsigned int mu;
        if (width == 4)      mu = ((const unsigned int*)adj)[(size_t)row * N_NODES + j];
        else if (width == 2) mu = ((const unsigned short*)adj)[(size_t)row * N_NODES + j];
        else                 mu = ((const unsigned char*)adj)[(size_t)row * N_NODES + j];
        if (mu) {
            float sc = si + sj_arr[j];
            sc = (sc >= 0.f) ? sc : NEG_SLOPE * sc;
            acc = fmaf(expf(sc - m), proj[(size_t)j * OUT_F + lane], acc);
        }
    }
    float h = acc / psum;
    if (f32o) ((float*)outv)[(size_t)row * OUT_F + lane] = h;
    else ((unsigned short*)outv)[(size_t)row * OUT_F + lane] = f2bf(h);
}

// ---------------------------------------------------------------------------
// DIAGNOSTIC PROBE (R11): 4 repeated count-only scans of each row, same
// nt-load/ballot structure as attn's scan. Runs AFTER attn (production path
// untouched). At 4x cost it exceeds the harness-fill floor (~158us) and
// surfaces in rocprof top-5 WITH counters. Memory-clobber barriers prevent
// load CSE across passes. counts[] write prevents DCE.
// ---------------------------------------------------------------------------
__global__ __launch_bounds__(256, 8) void scan_probe_kernel(
    const void* __restrict__ adj, const int* __restrict__ gflags,
    int* __restrict__ counts) {
    int tid = threadIdx.x, lane = tid & 63, wid = tid >> 6;
    int f = gflags[0];
    int width = (!(f & 1)) ? 4 : ((!(f & 2)) ? 2 : 1);
    int row = blockIdx.x * 4 + wid;
    int total = 0;

#pragma unroll 1
    for (int pass = 0; pass < 4; ++pass) {
        asm volatile("" ::: "memory");
        int base = 0;
        if (width == 4) {
            const v4u* p = (const v4u*)((const unsigned int*)adj + (size_t)row * N_NODES);
            v4u c0 = ntload(p + lane), c1 = ntload(p + lane + 64),
                c2 = ntload(p + lane + 128), c3 = ntload(p + lane + 192);
#pragma unroll 1
            for (int it = 0; it < 8; ++it) {
                v4u n0, n1, n2, n3;
                if (it < 7) {
                    int v = (it + 1) * 256 + lane;
                    n0 = ntload(p + v); n1 = ntload(p + v + 64);
                    n2 = ntload(p + v + 128); n3 = ntload(p + v + 192);
                }
#pragma unroll
                for (int q = 0; q < 4; ++q) {
                    v4u c = (q == 0) ? c0 : (q == 1) ? c1 : (q == 2) ? c2 : c3;
                    base += (int)__popcll(__ballot(c.x != 0u));
                    base += (int)__popcll(__ballot(c.y != 0u));
                    base += (int)__popcll(__ballot(c.z != 0u));
                    base += (int)__popcll(__ballot(c.w != 0u));
                }
                c0 = n0; c1 = n1; c2 = n2; c3 = n3;
            }
        } else {
            // cold widths: simple strided count (not the perf target)
            int n = (width == 2) ? N_NODES : N_NODES;
#pragma unroll 1
            for (int j = lane; j < n; j += 64) {
                unsigned int mu;
                if (width == 2) mu = ((const unsigned short*)adj)[(size_t)row * N_NODES + j];
                else            mu = ((const unsigned char*)adj)[(size_t)row * N_NODES + j];
                base += (int)__popcll(__ballot(mu != 0u)) ? 1 : 0;
            }
        }
        total += base;
    }
    if (lane == 0) counts[row] = total;
}

extern "C" void kernel_launch(void* const* d_in, const int* in_sizes, int n_in,
                              void* d_out, int out_size, void* d_ws, size_t ws_size,
                              hipStream_t stream) {
    const void* X   = d_in[0];  // [8192,256] fp32 (runtime-detected; bf16 fallback)
    const void* adj = d_in[1];  // [8192,8192] bool as int32 (runtime-detected)
    const void* W   = d_in[2];  // [256,64]
    const void* A   = d_in[3];  // [128,1]

    char* ws = (char*)d_ws;
    float* si     = (float*)ws;
    float* sj     = (float*)(ws + 32768);
    float* proj   = (float*)(ws + 65536);
    int*   gflag  = (int*)(ws + (3 << 20));
    int*   counts = (int*)(ws + (4 << 20));

    proj_kernel<<<N_NODES / 16, 256, 0, stream>>>(X, W, A, adj, proj, si, sj, gflag);
    attn_kernel<<<N_NODES / 4, 256, 0, stream>>>(adj, gflag, proj, si, sj, d_out);
    scan_probe_kernel<<<N_NODES / 4, 256, 0, stream>>>(adj, gflag, counts);
}

// Round 12
// 449.687 us; speedup vs baseline: 1.1827x; 1.1827x over previous
//
#include <hip/hip_runtime.h>
#include <hip/hip_bf16.h>
#include <stdint.h>

#define N_NODES 8192
#define IN_F    256
#define OUT_F   64
#define NEG_SLOPE 0.2f
#define CAP     512       // per-wave neighbor list; mean degree 82, sd 9 -> 47 sigma

typedef unsigned int v4u __attribute__((ext_vector_type(4)));

// Non-temporal 16B load (R9: -15us; R11 probe: scan at BW floor with these).
static __device__ __forceinline__ v4u ntload(const v4u* p) {
    return __builtin_nontemporal_load(p);
}

static __device__ __forceinline__ float bf2f(unsigned short u) {
    union { unsigned int i; float f; } v; v.i = ((unsigned int)u) << 16; return v.f;
}
static __device__ __forceinline__ float bflo(unsigned int u) {
    union { unsigned int i; float f; } v; v.i = u << 16; return v.f;
}
static __device__ __forceinline__ float bfhi(unsigned int u) {
    union { unsigned int i; float f; } v; v.i = u & 0xFFFF0000u; return v.f;
}
static __device__ __forceinline__ unsigned short f2bf(float f) {
    union { float f; unsigned int i; } v; v.f = f;
    unsigned int x = v.i;
    unsigned int lsb = (x >> 16) & 1u;
    x += 0x7FFFu + lsb;
    return (unsigned short)(x >> 16);
}

// ---------------------------------------------------------------------------
// proj = X @ W (fp32 accum), s_i = proj @ a[:64], s_j = proj @ a[64:]
// 512 blocks x 16 rows (R5-verified compute; R11 fused detection).
//   gflags[0]: adj width violations (bit0/1/2 -> not 4/2/1-byte elems);
//              width = 4 if !bit0 else 2 if !bit1 else 1.   R5-R11: 4.
//   gflags[1]: nonzero => X is fp32.                        R5-R11: fp32.
// ---------------------------------------------------------------------------
__global__ __launch_bounds__(256) void proj_kernel(
    const void* __restrict__ Xv, const void* __restrict__ Wv,
    const void* __restrict__ Av, const void* __restrict__ adjv,
    float* __restrict__ proj, float* __restrict__ si, float* __restrict__ sj,
    int* __restrict__ gflags) {
    __shared__ unsigned short wL[IN_F * OUT_F];  // 32 KB
    __shared__ unsigned short xL[16 * IN_F];     // 8 KB
    __shared__ float aL[2 * OUT_F];
    __shared__ int sdet[2];

    int tid = threadIdx.x;
    if (tid < 2) sdet[tid] = 0;
    __syncthreads();

    {
        const v4u* px = (const v4u*)Xv;
        v4u x0 = px[tid], x1 = px[tid + 256], x2 = px[tid + 512], x3 = px[tid + 768];
        int xf = 0;
#pragma unroll
        for (int k = 0; k < 4; ++k) {
            v4u a = (k == 0) ? x0 : (k == 1) ? x1 : (k == 2) ? x2 : x3;
#pragma unroll
            for (int h = 0; h < 4; ++h) {
                unsigned int v = (h == 0) ? a.x : (h == 1) ? a.y : (h == 2) ? a.z : a.w;
                unsigned int e0 = (v >> 7) & 0xFFu, e1 = (v >> 23) & 0xFFu;
                if (e0 >= 133u || e1 >= 133u) xf = 1;
            }
        }
        int viol = 0;
        if (blockIdx.x == 0) {
            const v4u* pa = (const v4u*)adjv;
            v4u a0 = pa[tid], a1 = pa[tid + 256], a2 = pa[tid + 512], a3 = pa[tid + 768];
#pragma unroll
            for (int k = 0; k < 4; ++k) {
                v4u a = (k == 0) ? a0 : (k == 1) ? a1 : (k == 2) ? a2 : a3;
#pragma unroll
                for (int h = 0; h < 4; ++h) {
                    unsigned int v = (h == 0) ? a.x : (h == 1) ? a.y : (h == 2) ? a.z : a.w;
                    if (v) {
                        if (v != 1u && v != 0x3F800000u) viol |= 1;
                        unsigned int h0 = v & 0xFFFFu, h1 = v >> 16;
                        if ((h0 != 0u && h0 != 1u && h0 != 0x3F80u) ||
                            (h1 != 0u && h1 != 1u && h1 != 0x3F80u)) viol |= 2;
                        unsigned int b0 = v & 0xFFu, b1 = (v >> 8) & 0xFFu,
                                     b2 = (v >> 16) & 0xFFu, b3 = v >> 24;
                        if (b0 > 1u || b1 > 1u || b2 > 1u || b3 > 1u) viol |= 4;
                    }
                }
            }
        }
        for (int o = 32; o; o >>= 1) {
            xf   |= __shfl_xor(xf, o, 64);
            viol |= __shfl_xor(viol, o, 64);
        }
        if ((tid & 63) == 0) {
            if (xf)   atomicOr(&sdet[1], 1);
            if (viol) atomicOr(&sdet[0], viol);
        }
    }
    __syncthreads();
    bool xf32 = (sdet[1] != 0);
    if (blockIdx.x == 0 && tid == 0) { gflags[0] = sdet[0]; gflags[1] = sdet[1]; }

    int row0 = blockIdx.x * 16;
    int tc = tid & 15;
    int r  = tid >> 4;
    int c0 = tc * 4;
    int row = row0 + r;

    float acc0 = 0.f, acc1 = 0.f, acc2 = 0.f, acc3 = 0.f;

    if (xf32) {
        const float* Xf = (const float*)Xv;
        const float* Wf = (const float*)Wv;
        const float* Af = (const float*)Av;
        if (tid < 2 * OUT_F) aL[tid] = Af[tid];
        __syncthreads();
        const float4* xr = (const float4*)(Xf + (size_t)row * IN_F);
#pragma unroll 2
        for (int kv = 0; kv < IN_F / 4; ++kv) {
            float4 xq = xr[kv];
#pragma unroll
            for (int t = 0; t < 4; ++t) {
                float x = (t == 0) ? xq.x : (t == 1) ? xq.y : (t == 2) ? xq.z : xq.w;
                float4 wq = *(const float4*)(Wf + (size_t)(kv * 4 + t) * OUT_F + c0);
                acc0 = fmaf(x, wq.x, acc0);
                acc1 = fmaf(x, wq.y, acc1);
                acc2 = fmaf(x, wq.z, acc2);
                acc3 = fmaf(x, wq.w, acc3);
            }
        }
    } else {
        const unsigned short* Xh = (const unsigned short*)Xv;
        const unsigned short* Wh = (const unsigned short*)Wv;
        const unsigned short* Ah = (const unsigned short*)Av;
        for (int i = tid; i < (IN_F * OUT_F) / 8; i += 256)
            ((uint4*)wL)[i] = ((const uint4*)Wh)[i];
        for (int i = tid; i < (16 * IN_F) / 8; i += 256)
            ((uint4*)xL)[i] = ((const uint4*)(Xh + (size_t)row0 * IN_F))[i];
        if (tid < 2 * OUT_F) aL[tid] = bf2f(Ah[tid]);
        __syncthreads();

        const uint4* xrv = (const uint4*)&xL[r * IN_F];
#pragma unroll 4
        for (int kv = 0; kv < IN_F / 8; ++kv) {
            uint4 xq = xrv[kv];
#pragma unroll
            for (int h = 0; h < 4; ++h) {
                unsigned int xp = (h == 0) ? xq.x : (h == 1) ? xq.y : (h == 2) ? xq.z : xq.w;
                int k0 = kv * 8 + h * 2;
                uint2 w0 = *(const uint2*)&wL[(k0 + 0) * OUT_F + c0];
                uint2 w1 = *(const uint2*)&wL[(k0 + 1) * OUT_F + c0];
                float xa = bflo(xp), xb = bfhi(xp);
                acc0 = fmaf(xa, bflo(w0.x), acc0);
                acc1 = fmaf(xa, bfhi(w0.x), acc1);
                acc2 = fmaf(xa, bflo(w0.y), acc2);
                acc3 = fmaf(xa, bfhi(w0.y), acc3);
                acc0 = fmaf(xb, bflo(w1.x), acc0);
                acc1 = fmaf(xb, bfhi(w1.x), acc1);
                acc2 = fmaf(xb, bflo(w1.y), acc2);
                acc3 = fmaf(xb, bfhi(w1.y), acc3);
            }
        }
    }

    *(float4*)&proj[(size_t)row * OUT_F + c0] = make_float4(acc0, acc1, acc2, acc3);

    float sa = acc0 * aL[c0] + acc1 * aL[c0 + 1] + acc2 * aL[c0 + 2] + acc3 * aL[c0 + 3];
    float sb = acc0 * aL[OUT_F + c0] + acc1 * aL[OUT_F + c0 + 1] +
               acc2 * aL[OUT_F + c0 + 2] + acc3 * aL[OUT_F + c0 + 3];
    for (int off = 8; off; off >>= 1) {
        sa += __shfl_xor(sa, off, 16);
        sb += __shfl_xor(sb, off, 16);
    }
    if (tc == 0) { si[row] = sa; sj[row] = sb; }
}

// Index-only ballot compaction: no global loads, no score math in the scan.
static __device__ __forceinline__ void compact_idx(
    bool hit, int j, int lane, unsigned long long mask_lt,
    int& base, int* __restrict__ idxL) {
    unsigned long long b = __ballot(hit);
    if (hit) {
        int pos = base + (int)__popcll(b & mask_lt);
        if (pos < CAP) idxL[pos] = j;
    }
    base += (int)__popcll(b);
}

// One full production attn pass for one row (scan + compact + phases + store).
// Idempotent: pure function of inputs.
static __device__ __forceinline__ void attn_row_pass(
    const void* __restrict__ adj, int width, bool f32o,
    const float* __restrict__ proj, const float* __restrict__ si_arr,
    const float* __restrict__ sj_arr, void* __restrict__ outv,
    int row, int lane, int* __restrict__ idxL, float* __restrict__ scL) {
    unsigned long long mask_lt = (1ull << lane) - 1ull;
    float si = si_arr[row];
    int base = 0;

    if (width == 4) {
        const v4u* p = (const v4u*)((const unsigned int*)adj + (size_t)row * N_NODES);
        v4u c0 = ntload(p + lane), c1 = ntload(p + lane + 64),
            c2 = ntload(p + lane + 128), c3 = ntload(p + lane + 192);
#pragma unroll 1
        for (int it = 0; it < 8; ++it) {
            v4u n0, n1, n2, n3;
            if (it < 7) {
                int v = (it + 1) * 256 + lane;
                n0 = ntload(p + v); n1 = ntload(p + v + 64);
                n2 = ntload(p + v + 128); n3 = ntload(p + v + 192);
            }
#pragma unroll
            for (int q = 0; q < 4; ++q) {
                v4u c = (q == 0) ? c0 : (q == 1) ? c1 : (q == 2) ? c2 : c3;
                int j0 = 4 * (it * 256 + lane + q * 64);
                compact_idx(c.x != 0u, j0 + 0, lane, mask_lt, base, idxL);
                compact_idx(c.y != 0u, j0 + 1, lane, mask_lt, base, idxL);
                compact_idx(c.z != 0u, j0 + 2, lane, mask_lt, base, idxL);
                compact_idx(c.w != 0u, j0 + 3, lane, mask_lt, base, idxL);
            }
            c0 = n0; c1 = n1; c2 = n2; c3 = n3;
        }
    } else if (width == 2) {
        const v4u* p = (const v4u*)((const unsigned short*)adj + (size_t)row * N_NODES);
#pragma unroll 1
        for (int it = 0; it < 4; ++it) {
            int v0 = it * 256 + lane;
            v4u c0 = ntload(p + v0), c1 = ntload(p + v0 + 64),
                c2 = ntload(p + v0 + 128), c3 = ntload(p + v0 + 192);
#pragma unroll
            for (int q = 0; q < 4; ++q) {
                v4u c = (q == 0) ? c0 : (q == 1) ? c1 : (q == 2) ? c2 : c3;
                int j0 = 8 * (v0 + q * 64);
#pragma unroll
                for (int h = 0; h < 4; ++h) {
                    unsigned int word = (h == 0) ? c.x : (h == 1) ? c.y : (h == 2) ? c.z : c.w;
                    compact_idx((word & 0xFFFFu) != 0u, j0 + 2 * h + 0, lane, mask_lt, base, idxL);
                    compact_idx((word >> 16)     != 0u, j0 + 2 * h + 1, lane, mask_lt, base, idxL);
                }
            }
        }
    } else {
        const v4u* p = (const v4u*)((const unsigned char*)adj + (size_t)row * N_NODES);
#pragma unroll 1
        for (int it = 0; it < 2; ++it) {
            int v0 = it * 256 + lane;
            v4u c0 = ntload(p + v0), c1 = ntload(p + v0 + 64),
                c2 = ntload(p + v0 + 128), c3 = ntload(p + v0 + 192);
#pragma unroll
            for (int q = 0; q < 4; ++q) {
                v4u c = (q == 0) ? c0 : (q == 1) ? c1 : (q == 2) ? c2 : c3;
                int j0 = 16 * (v0 + q * 64);
#pragma unroll
                for (int h = 0; h < 4; ++h) {
                    unsigned int word = (h == 0) ? c.x : (h == 1) ? c.y : (h == 2) ? c.z : c.w;
                    compact_idx(((word)       & 0xFFu) != 0u, j0 + 4 * h + 0, lane, mask_lt, base, idxL);
                    compact_idx(((word >> 8)  & 0xFFu) != 0u, j0 + 4 * h + 1, lane, mask_lt, base, idxL);
                    compact_idx(((word >> 16) & 0xFFu) != 0u, j0 + 4 * h + 2, lane, mask_lt, base, idxL);
                    compact_idx(((word >> 24)        ) != 0u, j0 + 4 * h + 3, lane, mask_lt, base, idxL);
                }
            }
        }
    }

    int cnt = base;

    if (cnt == 0) {
        float acc = 0.f;
#pragma unroll 4
        for (int j = 0; j < N_NODES; ++j) acc += proj[(size_t)j * OUT_F + lane];
        float h = acc * (1.0f / (float)N_NODES);
        if (f32o) ((float*)outv)[(size_t)row * OUT_F + lane] = h;
        else ((unsigned short*)outv)[(size_t)row * OUT_F + lane] = f2bf(h);
        return;
    }

    if (cnt <= CAP) {
        float m = -3.0e38f;
        for (int k = lane; k < cnt; k += 64) {
            int j = idxL[k];
            float sc = si + sj_arr[j];
            sc = (sc >= 0.f) ? sc : NEG_SLOPE * sc;
            scL[k] = sc;
            m = fmaxf(m, sc);
        }
        for (int o = 32; o; o >>= 1) m = fmaxf(m, __shfl_xor(m, o, 64));

        float psum = 0.f;
        for (int k = lane; k < cnt; k += 64) {
            float w = expf(scL[k] - m);
            scL[k] = w;
            psum += w;
        }
        for (int o = 32; o; o >>= 1) psum += __shfl_xor(psum, o, 64);
        float inv_denom = 1.0f / psum;

        float acc = 0.f;
#pragma unroll 4
        for (int k = 0; k < cnt; ++k)
            acc = fmaf(scL[k], proj[(size_t)idxL[k] * OUT_F + lane], acc);
        float h = acc * inv_denom;
        if (f32o) ((float*)outv)[(size_t)row * OUT_F + lane] = h;
        else ((unsigned short*)outv)[(size_t)row * OUT_F + lane] = f2bf(h);
        return;
    }

    // ---- overflow fallback (cnt > CAP): correct, slow, statistically never hit.
    float m = -3.0e38f;
#pragma unroll 1
    for (int j = lane; j < N_NODES; j += 64) {
        unsigned int mu;
        if (width == 4)      mu = ((const unsigned int*)adj)[(size_t)row * N_NODES + j];
        else if (width == 2) mu = ((const unsigned short*)adj)[(size_t)row * N_NODES + j];
        else                 mu = ((const unsigned char*)adj)[(size_t)row * N_NODES + j];
        if (mu) {
            float sc = si + sj_arr[j];
            sc = (sc >= 0.f) ? sc : NEG_SLOPE * sc;
            m = fmaxf(m, sc);
        }
    }
    for (int o = 32; o; o >>= 1) m = fmaxf(m, __shfl_xor(m, o, 64));
    float psum = 0.f;
#pragma unroll 1
    for (int j = lane; j < N_NODES; j += 64) {
        unsigned int mu;
        if (width == 4)      mu = ((const unsigned int*)adj)[(size_t)row * N_NODES + j];
        else if (width == 2) mu = ((const unsigned short*)adj)[(size_t)row * N_NODES + j];
        else                 mu = ((const unsigned char*)adj)[(size_t)row * N_NODES + j];
        if (mu) {
            float sc = si + sj_arr[j];
            sc = (sc >= 0.f) ? sc : NEG_SLOPE * sc;
            psum += expf(sc - m);
        }
    }
    for (int o = 32; o; o >>= 1) psum += __shfl_xor(psum, o, 64);
    float acc = 0.f;
#pragma unroll 1
    for (int j = 0; j < N_NODES; ++j) {
        unsigned int mu;
        if (width == 4)      mu = ((const unsigned int*)adj)[(size_t)row * N_NODES + j];
        else if (width == 2) mu = ((const unsigned short*)adj)[(size_t)row * N_NODES + j];
        else                 mu = ((const unsigned char*)adj)[(size_t)row * N_NODES + j];
        if (mu) {
            float sc = si + sj_arr[j];
            sc = (sc >= 0.f) ? sc : NEG_SLOPE * sc;
            acc = fmaf(expf(sc - m), proj[(size_t)j * OUT_F + lane], acc);
        }
    }
    float h = acc / psum;
    if (f32o) ((float*)outv)[(size_t)row * OUT_F + lane] = h;
    else ((unsigned short*)outv)[(size_t)row * OUT_F + lane] = f2bf(h);
}

// ---------------------------------------------------------------------------
// R12 DIAGNOSTIC: the full production attn pass runs TWICE per dispatch
// (idempotent — both passes write identical outputs). At ~2x90us the dispatch
// exceeds the harness-fill floor (~158us) and surfaces in rocprof top-5 with
// full counters for the REAL kernel. Memory clobber prevents cross-pass CSE.
// ---------------------------------------------------------------------------
__global__ __launch_bounds__(256, 8) void attn_kernel(
    const void* __restrict__ adj, const int* __restrict__ gflags,
    const float* __restrict__ proj, const float* __restrict__ si_arr,
    const float* __restrict__ sj_arr, void* __restrict__ outv) {
    __shared__ int   s_idx[4 * CAP];   // 8 KB (2 KB per wave)
    __shared__ float s_sc[4 * CAP];    // 8 KB (2 KB per wave)

    int tid  = threadIdx.x;
    int lane = tid & 63;
    int wid  = tid >> 6;

    int f = gflags[0];
    int width = (!(f & 1)) ? 4 : ((!(f & 2)) ? 2 : 1);
    bool f32o = (gflags[1] != 0);

    int row = blockIdx.x * 4 + wid;
    int*   idxL = &s_idx[wid * CAP];
    float* scL  = &s_sc[wid * CAP];

#pragma unroll 1
    for (int pass = 0; pass < 2; ++pass) {
        asm volatile("" ::: "memory");
        attn_row_pass(adj, width, f32o, proj, si_arr, sj_arr, outv,
                      row, lane, idxL, scL);
    }
}

extern "C" void kernel_launch(void* const* d_in, const int* in_sizes, int n_in,
                              void* d_out, int out_size, void* d_ws, size_t ws_size,
                              hipStream_t stream) {
    const void* X   = d_in[0];  // [8192,256] fp32 (runtime-detected; bf16 fallback)
    const void* adj = d_in[1];  // [8192,8192] bool as int32 (runtime-detected)
    const void* W   = d_in[2];  // [256,64]
    const void* A   = d_in[3];  // [128,1]

    char* ws = (char*)d_ws;
    float* si    = (float*)ws;
    float* sj    = (float*)(ws + 32768);
    float* proj  = (float*)(ws + 65536);
    int*   gflag = (int*)(ws + (3 << 20));

    proj_kernel<<<N_NODES / 16, 256, 0, stream>>>(X, W, A, adj, proj, si, sj, gflag);
    attn_kernel<<<N_NODES / 4, 256, 0, stream>>>(adj, gflag, proj, si, sj, d_out);
}

// Round 13
// 374.674 us; speedup vs baseline: 1.4195x; 1.2002x over previous
//
#include <hip/hip_runtime.h>
#include <hip/hip_bf16.h>
#include <stdint.h>

#define N_NODES 8192
#define IN_F    256
#define OUT_F   64
#define NEG_SLOPE 0.2f
#define CAP     512       // per-wave neighbor list; mean degree 82, sd 9 -> 47 sigma

typedef unsigned int v4u __attribute__((ext_vector_type(4)));

// Non-temporal 16B load (R9: -15us; R11 probe: scan at BW floor with these).
static __device__ __forceinline__ v4u ntload(const v4u* p) {
    return __builtin_nontemporal_load(p);
}

static __device__ __forceinline__ float bf2f(unsigned short u) {
    union { unsigned int i; float f; } v; v.i = ((unsigned int)u) << 16; return v.f;
}
static __device__ __forceinline__ float bflo(unsigned int u) {
    union { unsigned int i; float f; } v; v.i = u << 16; return v.f;
}
static __device__ __forceinline__ float bfhi(unsigned int u) {
    union { unsigned int i; float f; } v; v.i = u & 0xFFFF0000u; return v.f;
}
static __device__ __forceinline__ unsigned short f2bf(float f) {
    union { float f; unsigned int i; } v; v.f = f;
    unsigned int x = v.i;
    unsigned int lsb = (x >> 16) & 1u;
    x += 0x7FFFu + lsb;
    return (unsigned short)(x >> 16);
}

// ---------------------------------------------------------------------------
// proj = X @ W (fp32 accum), s_i = proj @ a[:64], s_j = proj @ a[64:]
// 512 blocks x 16 rows (R5-verified compute; R11 fused detection).
// Stores proj twice: fp32 (cold fallback paths) + bf16 (hot phase-3 gather,
// halves the ~172MB L3 gather stream — R12 post-mortem).
//   gflags[0]: adj width violations (bit0/1/2 -> not 4/2/1-byte elems);
//              width = 4 if !bit0 else 2 if !bit1 else 1.   R5-R12: 4.
//   gflags[1]: nonzero => X is fp32.                        R5-R12: fp32.
// ---------------------------------------------------------------------------
__global__ __launch_bounds__(256) void proj_kernel(
    const void* __restrict__ Xv, const void* __restrict__ Wv,
    const void* __restrict__ Av, const void* __restrict__ adjv,
    float* __restrict__ proj, unsigned short* __restrict__ projbf,
    float* __restrict__ si, float* __restrict__ sj,
    int* __restrict__ gflags) {
    __shared__ unsigned short wL[IN_F * OUT_F];  // 32 KB
    __shared__ unsigned short xL[16 * IN_F];     // 8 KB
    __shared__ float aL[2 * OUT_F];
    __shared__ int sdet[2];

    int tid = threadIdx.x;
    if (tid < 2) sdet[tid] = 0;
    __syncthreads();

    {
        const v4u* px = (const v4u*)Xv;
        v4u x0 = px[tid], x1 = px[tid + 256], x2 = px[tid + 512], x3 = px[tid + 768];
        int xf = 0;
#pragma unroll
        for (int k = 0; k < 4; ++k) {
            v4u a = (k == 0) ? x0 : (k == 1) ? x1 : (k == 2) ? x2 : x3;
#pragma unroll
            for (int h = 0; h < 4; ++h) {
                unsigned int v = (h == 0) ? a.x : (h == 1) ? a.y : (h == 2) ? a.z : a.w;
                unsigned int e0 = (v >> 7) & 0xFFu, e1 = (v >> 23) & 0xFFu;
                if (e0 >= 133u || e1 >= 133u) xf = 1;
            }
        }
        int viol = 0;
        if (blockIdx.x == 0) {
            const v4u* pa = (const v4u*)adjv;
            v4u a0 = pa[tid], a1 = pa[tid + 256], a2 = pa[tid + 512], a3 = pa[tid + 768];
#pragma unroll
            for (int k = 0; k < 4; ++k) {
                v4u a = (k == 0) ? a0 : (k == 1) ? a1 : (k == 2) ? a2 : a3;
#pragma unroll
                for (int h = 0; h < 4; ++h) {
                    unsigned int v = (h == 0) ? a.x : (h == 1) ? a.y : (h == 2) ? a.z : a.w;
                    if (v) {
                        if (v != 1u && v != 0x3F800000u) viol |= 1;
                        unsigned int h0 = v & 0xFFFFu, h1 = v >> 16;
                        if ((h0 != 0u && h0 != 1u && h0 != 0x3F80u) ||
                            (h1 != 0u && h1 != 1u && h1 != 0x3F80u)) viol |= 2;
                        unsigned int b0 = v & 0xFFu, b1 = (v >> 8) & 0xFFu,
                                     b2 = (v >> 16) & 0xFFu, b3 = v >> 24;
                        if (b0 > 1u || b1 > 1u || b2 > 1u || b3 > 1u) viol |= 4;
                    }
                }
            }
        }
        for (int o = 32; o; o >>= 1) {
            xf   |= __shfl_xor(xf, o, 64);
            viol |= __shfl_xor(viol, o, 64);
        }
        if ((tid & 63) == 0) {
            if (xf)   atomicOr(&sdet[1], 1);
            if (viol) atomicOr(&sdet[0], viol);
        }
    }
    __syncthreads();
    bool xf32 = (sdet[1] != 0);
    if (blockIdx.x == 0 && tid == 0) { gflags[0] = sdet[0]; gflags[1] = sdet[1]; }

    int row0 = blockIdx.x * 16;
    int tc = tid & 15;
    int r  = tid >> 4;
    int c0 = tc * 4;
    int row = row0 + r;

    float acc0 = 0.f, acc1 = 0.f, acc2 = 0.f, acc3 = 0.f;

    if (xf32) {
        const float* Xf = (const float*)Xv;
        const float* Wf = (const float*)Wv;
        const float* Af = (const float*)Av;
        if (tid < 2 * OUT_F) aL[tid] = Af[tid];
        __syncthreads();
        const float4* xr = (const float4*)(Xf + (size_t)row * IN_F);
#pragma unroll 2
        for (int kv = 0; kv < IN_F / 4; ++kv) {
            float4 xq = xr[kv];
#pragma unroll
            for (int t = 0; t < 4; ++t) {
                float x = (t == 0) ? xq.x : (t == 1) ? xq.y : (t == 2) ? xq.z : xq.w;
                float4 wq = *(const float4*)(Wf + (size_t)(kv * 4 + t) * OUT_F + c0);
                acc0 = fmaf(x, wq.x, acc0);
                acc1 = fmaf(x, wq.y, acc1);
                acc2 = fmaf(x, wq.z, acc2);
                acc3 = fmaf(x, wq.w, acc3);
            }
        }
    } else {
        const unsigned short* Xh = (const unsigned short*)Xv;
        const unsigned short* Wh = (const unsigned short*)Wv;
        const unsigned short* Ah = (const unsigned short*)Av;
        for (int i = tid; i < (IN_F * OUT_F) / 8; i += 256)
            ((uint4*)wL)[i] = ((const uint4*)Wh)[i];
        for (int i = tid; i < (16 * IN_F) / 8; i += 256)
            ((uint4*)xL)[i] = ((const uint4*)(Xh + (size_t)row0 * IN_F))[i];
        if (tid < 2 * OUT_F) aL[tid] = bf2f(Ah[tid]);
        __syncthreads();

        const uint4* xrv = (const uint4*)&xL[r * IN_F];
#pragma unroll 4
        for (int kv = 0; kv < IN_F / 8; ++kv) {
            uint4 xq = xrv[kv];
#pragma unroll
            for (int h = 0; h < 4; ++h) {
                unsigned int xp = (h == 0) ? xq.x : (h == 1) ? xq.y : (h == 2) ? xq.z : xq.w;
                int k0 = kv * 8 + h * 2;
                uint2 w0 = *(const uint2*)&wL[(k0 + 0) * OUT_F + c0];
                uint2 w1 = *(const uint2*)&wL[(k0 + 1) * OUT_F + c0];
                float xa = bflo(xp), xb = bfhi(xp);
                acc0 = fmaf(xa, bflo(w0.x), acc0);
                acc1 = fmaf(xa, bfhi(w0.x), acc1);
                acc2 = fmaf(xa, bflo(w0.y), acc2);
                acc3 = fmaf(xa, bfhi(w0.y), acc3);
                acc0 = fmaf(xb, bflo(w1.x), acc0);
                acc1 = fmaf(xb, bfhi(w1.x), acc1);
                acc2 = fmaf(xb, bflo(w1.y), acc2);
                acc3 = fmaf(xb, bfhi(w1.y), acc3);
            }
        }
    }

    *(float4*)&proj[(size_t)row * OUT_F + c0] = make_float4(acc0, acc1, acc2, acc3);
    // bf16 copy for the hot phase-3 gather (pack 4 bf16 into uint2)
    uint2 pb;
    pb.x = (unsigned int)f2bf(acc0) | ((unsigned int)f2bf(acc1) << 16);
    pb.y = (unsigned int)f2bf(acc2) | ((unsigned int)f2bf(acc3) << 16);
    *(uint2*)&projbf[(size_t)row * OUT_F + c0] = pb;

    float sa = acc0 * aL[c0] + acc1 * aL[c0 + 1] + acc2 * aL[c0 + 2] + acc3 * aL[c0 + 3];
    float sb = acc0 * aL[OUT_F + c0] + acc1 * aL[OUT_F + c0 + 1] +
               acc2 * aL[OUT_F + c0 + 2] + acc3 * aL[OUT_F + c0 + 3];
    for (int off = 8; off; off >>= 1) {
        sa += __shfl_xor(sa, off, 16);
        sb += __shfl_xor(sb, off, 16);
    }
    if (tc == 0) { si[row] = sa; sj[row] = sb; }
}

// Index-only ballot compaction: no global loads, no score math in the scan.
static __device__ __forceinline__ void compact_idx(
    bool hit, int j, int lane, unsigned long long mask_lt,
    int& base, int* __restrict__ idxL) {
    unsigned long long b = __ballot(hit);
    if (hit) {
        int pos = base + (int)__popcll(b & mask_lt);
        if (pos < CAP) idxL[pos] = j;
    }
    base += (int)__popcll(b);
}

// ---------------------------------------------------------------------------
// Fused masked softmax + h_out = attn @ proj. ONE ROW PER WAVE, nt loads,
// no per-block detection (reads gflags). Phase-3 gathers the bf16 proj copy
// (half the L3 traffic). 2048 blocks x 4 waves. Single pass (production).
// ---------------------------------------------------------------------------
__global__ __launch_bounds__(256, 8) void attn_kernel(
    const void* __restrict__ adj, const int* __restrict__ gflags,
    const float* __restrict__ proj, const unsigned short* __restrict__ projbf,
    const float* __restrict__ si_arr, const float* __restrict__ sj_arr,
    void* __restrict__ outv) {
    __shared__ int   s_idx[4 * CAP];   // 8 KB (2 KB per wave)
    __shared__ float s_sc[4 * CAP];    // 8 KB (2 KB per wave)

    int tid  = threadIdx.x;
    int lane = tid & 63;
    int wid  = tid >> 6;

    int f = gflags[0];
    int width = (!(f & 1)) ? 4 : ((!(f & 2)) ? 2 : 1);
    bool f32o = (gflags[1] != 0);

    int row = blockIdx.x * 4 + wid;
    int*   idxL = &s_idx[wid * CAP];
    float* scL  = &s_sc[wid * CAP];

    unsigned long long mask_lt = (1ull << lane) - 1ull;
    float si = si_arr[row];
    int base = 0;   // wave-uniform neighbor count

    if (width == 4) {
        const v4u* p = (const v4u*)((const unsigned int*)adj + (size_t)row * N_NODES);
        v4u c0 = ntload(p + lane), c1 = ntload(p + lane + 64),
            c2 = ntload(p + lane + 128), c3 = ntload(p + lane + 192);
#pragma unroll 1
        for (int it = 0; it < 8; ++it) {
            v4u n0, n1, n2, n3;
            if (it < 7) {
                int v = (it + 1) * 256 + lane;
                n0 = ntload(p + v); n1 = ntload(p + v + 64);
                n2 = ntload(p + v + 128); n3 = ntload(p + v + 192);
            }
#pragma unroll
            for (int q = 0; q < 4; ++q) {
                v4u c = (q == 0) ? c0 : (q == 1) ? c1 : (q == 2) ? c2 : c3;
                int j0 = 4 * (it * 256 + lane + q * 64);
                compact_idx(c.x != 0u, j0 + 0, lane, mask_lt, base, idxL);
                compact_idx(c.y != 0u, j0 + 1, lane, mask_lt, base, idxL);
                compact_idx(c.z != 0u, j0 + 2, lane, mask_lt, base, idxL);
                compact_idx(c.w != 0u, j0 + 3, lane, mask_lt, base, idxL);
            }
            c0 = n0; c1 = n1; c2 = n2; c3 = n3;
        }
    } else if (width == 2) {
        const v4u* p = (const v4u*)((const unsigned short*)adj + (size_t)row * N_NODES);
#pragma unroll 1
        for (int it = 0; it < 4; ++it) {
            int v0 = it * 256 + lane;
            v4u c0 = ntload(p + v0), c1 = ntload(p + v0 + 64),
                c2 = ntload(p + v0 + 128), c3 = ntload(p + v0 + 192);
#pragma unroll
            for (int q = 0; q < 4; ++q) {
                v4u c = (q == 0) ? c0 : (q == 1) ? c1 : (q == 2) ? c2 : c3;
                int j0 = 8 * (v0 + q * 64);
#pragma unroll
                for (int h = 0; h < 4; ++h) {
                    unsigned int word = (h == 0) ? c.x : (h == 1) ? c.y : (h == 2) ? c.z : c.w;
                    compact_idx((word & 0xFFFFu) != 0u, j0 + 2 * h + 0, lane, mask_lt, base, idxL);
                    compact_idx((word >> 16)     != 0u, j0 + 2 * h + 1, lane, mask_lt, base, idxL);
                }
            }
        }
    } else {
        const v4u* p = (const v4u*)((const unsigned char*)adj + (size_t)row * N_NODES);
#pragma unroll 1
        for (int it = 0; it < 2; ++it) {
            int v0 = it * 256 + lane;
            v4u c0 = ntload(p + v0), c1 = ntload(p + v0 + 64),
                c2 = ntload(p + v0 + 128), c3 = ntload(p + v0 + 192);
#pragma unroll
            for (int q = 0; q < 4; ++q) {
                v4u c = (q == 0) ? c0 : (q == 1) ? c1 : (q == 2) ? c2 : c3;
                int j0 = 16 * (v0 + q * 64);
#pragma unroll
                for (int h = 0; h < 4; ++h) {
                    unsigned int word = (h == 0) ? c.x : (h == 1) ? c.y : (h == 2) ? c.z : c.w;
                    compact_idx(((word)       & 0xFFu) != 0u, j0 + 4 * h + 0, lane, mask_lt, base, idxL);
                    compact_idx(((word >> 8)  & 0xFFu) != 0u, j0 + 4 * h + 1, lane, mask_lt, base, idxL);
                    compact_idx(((word >> 16) & 0xFFu) != 0u, j0 + 4 * h + 2, lane, mask_lt, base, idxL);
                    compact_idx(((word >> 24)        ) != 0u, j0 + 4 * h + 3, lane, mask_lt, base, idxL);
                }
            }
        }
    }

    int cnt = base;

    if (cnt == 0) {
        // all-NEG_BIG row -> uniform softmax -> column mean of proj (never hit)
        float acc = 0.f;
#pragma unroll 4
        for (int j = 0; j < N_NODES; ++j) acc += proj[(size_t)j * OUT_F + lane];
        float h = acc * (1.0f / (float)N_NODES);
        if (f32o) ((float*)outv)[(size_t)row * OUT_F + lane] = h;
        else ((unsigned short*)outv)[(size_t)row * OUT_F + lane] = f2bf(h);
        return;
    }

    if (cnt <= CAP) {
        // phase 2: scores from compacted list — <=2 parallel sj gathers/lane
        float m = -3.0e38f;
        for (int k = lane; k < cnt; k += 64) {
            int j = idxL[k];
            float sc = si + sj_arr[j];
            sc = (sc >= 0.f) ? sc : NEG_SLOPE * sc;
            scL[k] = sc;
            m = fmaxf(m, sc);
        }
        for (int o = 32; o; o >>= 1) m = fmaxf(m, __shfl_xor(m, o, 64));

        float psum = 0.f;
        for (int k = lane; k < cnt; k += 64) {
            float w = expf(scL[k] - m);
            scL[k] = w;
            psum += w;
        }
        for (int o = 32; o; o >>= 1) psum += __shfl_xor(psum, o, 64);
        float inv_denom = 1.0f / psum;

        // phase 3: gather bf16 proj — lane = column; 128B/row-visit from L3
        float acc = 0.f;
#pragma unroll 4
        for (int k = 0; k < cnt; ++k)
            acc = fmaf(scL[k], bf2f(projbf[(size_t)idxL[k] * OUT_F + lane]), acc);
        float h = acc * inv_denom;
        if (f32o) ((float*)outv)[(size_t)row * OUT_F + lane] = h;
        else ((unsigned short*)outv)[(size_t)row * OUT_F + lane] = f2bf(h);
        return;
    }

    // ---- overflow fallback (cnt > CAP): correct, slow, statistically never hit.
    float m = -3.0e38f;
#pragma unroll 1
    for (int j = lane; j < N_NODES; j += 64) {
        unsigned int mu;
        if (width == 4)      mu = ((const unsigned int*)adj)[(size_t)row * N_NODES + j];
        else if (width == 2) mu = ((const unsigned short*)adj)[(size_t)row * N_NODES + j];
        else                 mu = ((const unsigned char*)adj)[(size_t)row * N_NODES + j];
        if (mu) {
            float sc = si + sj_arr[j];
            sc = (sc >= 0.f) ? sc : NEG_SLOPE * sc;
            m = fmaxf(m, sc);
        }
    }
    for (int o = 32; o; o >>= 1) m = fmaxf(m, __shfl_xor(m, o, 64));
    float psum = 0.f;
#pragma unroll 1
    for (int j = lane; j < N_NODES; j += 64) {
        unsigned int mu;
        if (width == 4)      mu = ((const unsigned int*)adj)[(size_t)row * N_NODES + j];
        else if (width == 2) mu = ((const unsigned short*)adj)[(size_t)row * N_NODES + j];
        else                 mu = ((const unsigned char*)adj)[(size_t)row * N_NODES + j];
        if (mu) {
            float sc = si + sj_arr[j];
            sc = (sc >= 0.f) ? sc : NEG_SLOPE * sc;
            psum += expf(sc - m);
        }
    }
    for (int o = 32; o; o >>= 1) psum += __shfl_xor(psum, o, 64);
    float acc = 0.f;
#pragma unroll 1
    for (int j = 0; j < N_NODES; ++j) {
        unsigned int mu;
        if (width == 4)      mu = ((const unsigned int*)adj)[(size_t)row * N_NODES + j];
        else if (width == 2) mu = ((const unsigned short*)adj)[(size_t)row * N_NODES + j];
        else                 mu = ((const unsigned char*)adj)[(size_t)row * N_NODES + j];
        if (mu) {
            float sc = si + sj_arr[j];
            sc = (sc >= 0.f) ? sc : NEG_SLOPE * sc;
            acc = fmaf(expf(sc - m), proj[(size_t)j * OUT_F + lane], acc);
        }
    }
    float h = acc / psum;
    if (f32o) ((float*)outv)[(size_t)row * OUT_F + lane] = h;
    else ((unsigned short*)outv)[(size_t)row * OUT_F + lane] = f2bf(h);
}

extern "C" void kernel_launch(void* const* d_in, const int* in_sizes, int n_in,
                              void* d_out, int out_size, void* d_ws, size_t ws_size,
                              hipStream_t stream) {
    const void* X   = d_in[0];  // [8192,256] fp32 (runtime-detected; bf16 fallback)
    const void* adj = d_in[1];  // [8192,8192] bool as int32 (runtime-detected)
    const void* W   = d_in[2];  // [256,64]
    const void* A   = d_in[3];  // [128,1]

    char* ws = (char*)d_ws;
    float*          si     = (float*)ws;
    float*          sj     = (float*)(ws + 32768);
    float*          proj   = (float*)(ws + 65536);
    unsigned short* projbf = (unsigned short*)(ws + 65536 + (N_NODES * OUT_F * 4));
    int*            gflag  = (int*)(ws + (3 << 20));

    proj_kernel<<<N_NODES / 16, 256, 0, stream>>>(X, W, A, adj, proj, projbf,
                                                  si, sj, gflag);
    attn_kernel<<<N_NODES / 4, 256, 0, stream>>>(adj, gflag, proj, projbf,
                                                 si, sj, d_out);
}